// Round 1
// baseline (2718.975 us; speedup 1.0000x reference)
//
#include <hip/hip_runtime.h>

#define T_SEQ 2048
#define DMODEL 1024
#define NH 16
#define HD 64
// tokens total = B*T = 8192

// ---------------------------------------------------------------------------
// QKV GEMM: x[8192,1024] @ w_qkv[1024,3072] + b_qkv -> scatter to q/k/v
// each laid out [B,H,T,HD]. Tile 64x64, BK=16, 256 threads, 4x4 acc/thread.
// ---------------------------------------------------------------------------
__global__ __launch_bounds__(256) void qkv_gemm_kernel(
    const float* __restrict__ A, const float* __restrict__ Bw,
    const float* __restrict__ bias,
    float* __restrict__ qo, float* __restrict__ ko, float* __restrict__ vo)
{
    __shared__ float As[16][65];   // As[k][m], padded
    __shared__ float Bs[16][64];   // Bs[k][n]
    const int tid = threadIdx.x;
    const int m0 = blockIdx.y * 64;
    const int n0 = blockIdx.x * 64;
    const int tx = tid & 15;
    const int ty = tid >> 4;
    const int arow = tid >> 2, acol = (tid & 3) << 2;
    const int brow = tid >> 4, bcol = (tid & 15) << 2;
    float acc[4][4] = {};
    for (int k0 = 0; k0 < DMODEL; k0 += 16) {
        const float4 av = *(const float4*)&A[(size_t)(m0 + arow) * DMODEL + k0 + acol];
        const float4 bv = *(const float4*)&Bw[(size_t)(k0 + brow) * 3072 + n0 + bcol];
        __syncthreads();
        As[acol + 0][arow] = av.x;
        As[acol + 1][arow] = av.y;
        As[acol + 2][arow] = av.z;
        As[acol + 3][arow] = av.w;
        *(float4*)&Bs[brow][bcol] = bv;
        __syncthreads();
#pragma unroll
        for (int kk = 0; kk < 16; ++kk) {
            float ar[4], br[4];
#pragma unroll
            for (int i = 0; i < 4; ++i) ar[i] = As[kk][ty * 4 + i];
#pragma unroll
            for (int j = 0; j < 4; ++j) br[j] = Bs[kk][tx * 4 + j];
#pragma unroll
            for (int i = 0; i < 4; ++i)
#pragma unroll
                for (int j = 0; j < 4; ++j) acc[i][j] += ar[i] * br[j];
        }
    }
    // n0 is a multiple of 64 => whole block lands in one head of one of q/k/v
    const int which = n0 >> 10;           // /1024
    const int h = (n0 & 1023) >> 6;       // /64
    float* dst = which == 0 ? qo : (which == 1 ? ko : vo);
#pragma unroll
    for (int i = 0; i < 4; ++i) {
        const int m = m0 + ty * 4 + i;
        const int bb = m >> 11;           // /2048
        const int t = m & 2047;
#pragma unroll
        for (int j = 0; j < 4; ++j) {
            const int d = tx * 4 + j;
            const float val = acc[i][j] + bias[n0 + d];
            dst[(((size_t)(bb * NH + h)) * T_SEQ + t) * HD + d] = val;
        }
    }
}

// ---------------------------------------------------------------------------
// Flash-style causal attention. One block per (b,h,q-tile of 64 rows).
// K/V tiles of 32 rows. Online softmax (m,l,alpha in LDS).
// S kept transposed St[j][r] so every LDS pattern is <=2-way bank aliased.
// ---------------------------------------------------------------------------
__global__ __launch_bounds__(256) void attn_kernel(
    const float* __restrict__ q, const float* __restrict__ k,
    const float* __restrict__ v, float* __restrict__ y)
{
    __shared__ float Qt[64][64];    // Qt[d][r]
    __shared__ float Ks[32][64];    // Ks[j][d]
    __shared__ float Vs[32][64];    // Vs[j][d]
    __shared__ float St[32][64];    // St[j][r]
    __shared__ float mrow[64], lrow[64], asc[64];

    const int qi = blockIdx.x, h = blockIdx.y, b = blockIdx.z;
    const int q0 = qi * 64;
    const size_t head_off = ((size_t)(b * NH + h)) * T_SEQ * HD;
    const float* qb = q + head_off;
    const float* kb = k + head_off;
    const float* vb = v + head_off;

    const int tid = threadIdx.x;
    const int lane = tid & 63;
    const int wv = tid >> 6;   // 0..3

    // stage Q tile transposed (once per block; write conflicts negligible)
    {
        const int col = (tid & 15) * 4;
#pragma unroll
        for (int it = 0; it < 4; ++it) {
            const int row = (tid >> 4) + it * 16;
            const float4 t4 = *(const float4*)&qb[(size_t)(q0 + row) * HD + col];
            Qt[col + 0][row] = t4.x;
            Qt[col + 1][row] = t4.y;
            Qt[col + 2][row] = t4.z;
            Qt[col + 3][row] = t4.w;
        }
    }
    if (tid < 64) { mrow[tid] = -1e30f; lrow[tid] = 0.0f; }

    float o[16];
#pragma unroll
    for (int i = 0; i < 16; ++i) o[i] = 0.0f;

    const int krow = tid >> 3;          // 0..31
    const int kcol = (tid & 7) * 8;     // 0..56

    const int nkt = 2 * (qi + 1);
    for (int kt = 0; kt < nkt; ++kt) {
        const int j0 = kt * 32;
        const float4 ka = *(const float4*)&kb[(size_t)(j0 + krow) * HD + kcol];
        const float4 kb4 = *(const float4*)&kb[(size_t)(j0 + krow) * HD + kcol + 4];
        const float4 va = *(const float4*)&vb[(size_t)(j0 + krow) * HD + kcol];
        const float4 vb4 = *(const float4*)&vb[(size_t)(j0 + krow) * HD + kcol + 4];
        __syncthreads();   // prev iter readers of Ks/Vs/St are done
        *(float4*)&Ks[krow][kcol] = ka;
        *(float4*)&Ks[krow][kcol + 4] = kb4;
        *(float4*)&Vs[krow][kcol] = va;
        *(float4*)&Vs[krow][kcol + 4] = vb4;
        __syncthreads();

        // scores: r = lane, j = wv*8 + jj
        float sacc[8];
#pragma unroll
        for (int jj = 0; jj < 8; ++jj) sacc[jj] = 0.0f;
#pragma unroll 8
        for (int d = 0; d < HD; ++d) {
            const float qv = Qt[d][lane];
#pragma unroll
            for (int jj = 0; jj < 8; ++jj)
                sacc[jj] += qv * Ks[wv * 8 + jj][d];
        }
#pragma unroll
        for (int jj = 0; jj < 8; ++jj) {
            const int jg = j0 + wv * 8 + jj;
            float s = sacc[jj] * 0.125f;            // HD^-0.5
            if (jg > q0 + lane) s = -1e30f;          // causal mask
            St[wv * 8 + jj][lane] = s;
        }
        __syncthreads();

        // online softmax, one wave
        if (tid < 64) {
            const int r = tid;
            const float mold = mrow[r];
            float mt = mold;
#pragma unroll
            for (int j = 0; j < 32; ++j) mt = fmaxf(mt, St[j][r]);
            float lsum = 0.0f;
#pragma unroll
            for (int j = 0; j < 32; ++j) {
                const float p = __expf(St[j][r] - mt);
                St[j][r] = p;
                lsum += p;
            }
            const float alpha = __expf(mold - mt);
            lrow[r] = lrow[r] * alpha + lsum;
            mrow[r] = mt;
            asc[r] = alpha;
        }
        __syncthreads();

        // O update: d = lane, rows wv*16 + rr
#pragma unroll
        for (int rr = 0; rr < 16; ++rr) o[rr] *= asc[wv * 16 + rr];
        for (int j = 0; j < 32; ++j) {
            const float vv = Vs[j][lane];
#pragma unroll
            for (int rr = 0; rr < 16; ++rr)
                o[rr] += St[j][wv * 16 + rr] * vv;
        }
    }

    // write y in [B,T,D] layout (pre-projection)
#pragma unroll
    for (int rr = 0; rr < 16; ++rr) {
        const int r = wv * 16 + rr;
        const float val = o[rr] / lrow[r];
        y[((size_t)(b * T_SEQ + q0 + r)) * DMODEL + h * HD + lane] = val;
    }
}

// ---------------------------------------------------------------------------
// Output projection: y[8192,1024] @ w_proj[1024,1024] + b_proj -> out
// ---------------------------------------------------------------------------
__global__ __launch_bounds__(256) void proj_gemm_kernel(
    const float* __restrict__ A, const float* __restrict__ Bw,
    const float* __restrict__ bias, float* __restrict__ C)
{
    __shared__ float As[16][65];
    __shared__ float Bs[16][64];
    const int tid = threadIdx.x;
    const int m0 = blockIdx.y * 64;
    const int n0 = blockIdx.x * 64;
    const int tx = tid & 15;
    const int ty = tid >> 4;
    const int arow = tid >> 2, acol = (tid & 3) << 2;
    const int brow = tid >> 4, bcol = (tid & 15) << 2;
    float acc[4][4] = {};
    for (int k0 = 0; k0 < DMODEL; k0 += 16) {
        const float4 av = *(const float4*)&A[(size_t)(m0 + arow) * DMODEL + k0 + acol];
        const float4 bv = *(const float4*)&Bw[(size_t)(k0 + brow) * DMODEL + n0 + bcol];
        __syncthreads();
        As[acol + 0][arow] = av.x;
        As[acol + 1][arow] = av.y;
        As[acol + 2][arow] = av.z;
        As[acol + 3][arow] = av.w;
        *(float4*)&Bs[brow][bcol] = bv;
        __syncthreads();
#pragma unroll
        for (int kk = 0; kk < 16; ++kk) {
            float ar[4], br[4];
#pragma unroll
            for (int i = 0; i < 4; ++i) ar[i] = As[kk][ty * 4 + i];
#pragma unroll
            for (int j = 0; j < 4; ++j) br[j] = Bs[kk][tx * 4 + j];
#pragma unroll
            for (int i = 0; i < 4; ++i)
#pragma unroll
                for (int j = 0; j < 4; ++j) acc[i][j] += ar[i] * br[j];
        }
    }
#pragma unroll
    for (int i = 0; i < 4; ++i) {
        const int m = m0 + ty * 4 + i;
#pragma unroll
        for (int j = 0; j < 4; ++j) {
            const int n = n0 + tx * 4 + j;
            C[(size_t)m * DMODEL + n] = acc[i][j] + bias[n];
        }
    }
}

extern "C" void kernel_launch(void* const* d_in, const int* in_sizes, int n_in,
                              void* d_out, int out_size, void* d_ws, size_t ws_size,
                              hipStream_t stream) {
    const float* x      = (const float*)d_in[0];   // [4,2048,1024]
    const float* w_qkv  = (const float*)d_in[1];   // [1024,3072]
    const float* b_qkv  = (const float*)d_in[2];   // [3072]
    const float* w_proj = (const float*)d_in[3];   // [1024,1024]
    const float* b_proj = (const float*)d_in[4];   // [1024]
    float* out = (float*)d_out;                    // [4,2048,1024]

    const size_t perbuf = (size_t)4 * NH * T_SEQ * HD;  // 8388608 floats
    float* qws = (float*)d_ws;
    float* kws = qws + perbuf;
    float* vws = kws + perbuf;
    float* yws = vws + perbuf;

    qkv_gemm_kernel<<<dim3(3072 / 64, 8192 / 64), 256, 0, stream>>>(
        x, w_qkv, b_qkv, qws, kws, vws);
    attn_kernel<<<dim3(T_SEQ / 64, NH, 4), 256, 0, stream>>>(
        qws, kws, vws, yws);
    proj_gemm_kernel<<<dim3(DMODEL / 64, 8192 / 64), 256, 0, stream>>>(
        yws, w_proj, b_proj, out);
}

// Round 2
// 546.015 us; speedup vs baseline: 4.9797x; 4.9797x over previous
//
#include <hip/hip_runtime.h>
#include <hip/hip_bf16.h>

typedef unsigned short u16;
typedef short short8 __attribute__((ext_vector_type(8)));
typedef float f32x4 __attribute__((ext_vector_type(4)));

#define B_SZ 4
#define T_SEQ 2048
#define DMODEL 1024
#define NH 16
#define HD 64
#define QKV_ELEMS 8388608ull  // B*NH*T*HD = 4*16*2048*64

__device__ __forceinline__ u16 f2bf(float f) {
    __hip_bfloat16 h = __float2bfloat16(f);
    return __builtin_bit_cast(u16, h);
}

// async global->LDS, 16B per lane. LDS dest must be wave-uniform base; HW
// writes lane i at base + 16*i. We realize the XOR swizzle by permuting the
// SOURCE addresses per lane instead of the (fixed) destination.
__device__ __forceinline__ void gload16(const void* g, void* l) {
    __builtin_amdgcn_global_load_lds(
        (const __attribute__((address_space(1))) unsigned int*)g,
        (__attribute__((address_space(3))) unsigned int*)l, 16, 0, 0);
}

// ---------------------------------------------------------------------------
// cast x (fp32 -> bf16), element-wise
// ---------------------------------------------------------------------------
__global__ __launch_bounds__(256) void cast_x_kernel(
    const float4* __restrict__ x, u16* __restrict__ xb)
{
    const int i = blockIdx.x * 256 + threadIdx.x;   // exact grid
    const float4 v = x[i];
    union { u16 u[4]; uint2 d; } p;
    p.u[0] = f2bf(v.x); p.u[1] = f2bf(v.y); p.u[2] = f2bf(v.z); p.u[3] = f2bf(v.w);
    *(uint2*)(xb + (size_t)i * 4) = p.d;
}

// ---------------------------------------------------------------------------
// transpose+cast weights: w[K][N] fp32 -> wt[N][K] bf16
// reads coalesced over n (lanes), writes 16B per thread along k
// ---------------------------------------------------------------------------
__global__ __launch_bounds__(256) void tcast_kernel(
    const float* __restrict__ w, u16* __restrict__ wt, int K, int N)
{
    const int n = blockIdx.x * 256 + threadIdx.x;
    const int k0 = blockIdx.y * 256;
    for (int kk = 0; kk < 256; kk += 8) {
        short8 o;
#pragma unroll
        for (int e = 0; e < 8; ++e)
            o[e] = (short)f2bf(w[(size_t)(k0 + kk + e) * N + n]);
        *(short8*)&wt[(size_t)n * K + k0 + kk] = o;
    }
}

// ---------------------------------------------------------------------------
// bf16 MFMA GEMM: A[8192][1024] @ Bt[N][1024]^T, tile 128x128, BK=64.
// LDS rows = 64 bf16 = 128 B = 8 chunks of 16B, XOR-swizzled by (row&7).
// EPI=0: +bias, scatter bf16 into q/k/v [B,H,T,HD].  EPI=1: +bias, fp32 out.
// ---------------------------------------------------------------------------
template <int EPI>
__global__ __launch_bounds__(256) void gemm_kernel(
    const u16* __restrict__ A, const u16* __restrict__ Bt,
    const float* __restrict__ bias, void* __restrict__ outp)
{
    __shared__ u16 As[128 * 64];
    __shared__ u16 Bs[128 * 64];
    const int tid = threadIdx.x;
    const int l = tid & 63;
    const int w = tid >> 6;
    const int wm = w >> 1, wn = w & 1;
    const int m0 = blockIdx.y * 128, n0 = blockIdx.x * 128;
    const int srow = l >> 3;                // staging row within 8-row chunk
    const int sch  = (l & 7) ^ srow;        // swizzled source chunk
    const int fr = l & 15, fq = l >> 4;

    f32x4 acc[4][4] = {};

    for (int k0 = 0; k0 < 1024; k0 += 64) {
        __syncthreads();
#pragma unroll
        for (int ii = 0; ii < 4; ++ii) {
            const int row = w * 32 + ii * 8;
            gload16(&A[(size_t)(m0 + row + srow) * 1024 + k0 + sch * 8], &As[row * 64]);
            gload16(&Bt[(size_t)(n0 + row + srow) * 1024 + k0 + sch * 8], &Bs[row * 64]);
        }
        __syncthreads();
#pragma unroll
        for (int ks = 0; ks < 2; ++ks) {
            short8 af[4], bf[4];
#pragma unroll
            for (int t = 0; t < 4; ++t) {
                const int ar = wm * 64 + t * 16 + fr;
                af[t] = *(const short8*)&As[ar * 64 + (((ks * 4 + fq) ^ (l & 7)) << 3)];
                const int br = wn * 64 + t * 16 + fr;
                bf[t] = *(const short8*)&Bs[br * 64 + (((ks * 4 + fq) ^ (l & 7)) << 3)];
            }
#pragma unroll
            for (int mt = 0; mt < 4; ++mt)
#pragma unroll
                for (int nt = 0; nt < 4; ++nt)
                    acc[mt][nt] = __builtin_amdgcn_mfma_f32_16x16x32_bf16(
                        af[mt], bf[nt], acc[mt][nt], 0, 0, 0);
        }
    }

    if (EPI == 0) {
        u16* qkv = (u16*)outp;
#pragma unroll
        for (int nt = 0; nt < 4; ++nt) {
            const int n = n0 + wn * 64 + nt * 16 + fr;
            const float bs = bias[n];
            const int which = n >> 10, hh = (n >> 6) & 15, d = n & 63;
            u16* dst = qkv + (size_t)which * QKV_ELEMS + (size_t)hh * T_SEQ * HD + d;
#pragma unroll
            for (int mt = 0; mt < 4; ++mt)
#pragma unroll
                for (int r = 0; r < 4; ++r) {
                    const int m = m0 + wm * 64 + mt * 16 + fq * 4 + r;
                    const int bb = m >> 11, t = m & 2047;
                    dst[(size_t)bb * (NH * T_SEQ * HD) + (size_t)t * HD] =
                        f2bf(acc[mt][nt][r] + bs);
                }
        }
    } else {
        float* C = (float*)outp;
#pragma unroll
        for (int nt = 0; nt < 4; ++nt) {
            const int n = n0 + wn * 64 + nt * 16 + fr;
            const float bs = bias[n];
#pragma unroll
            for (int mt = 0; mt < 4; ++mt)
#pragma unroll
                for (int r = 0; r < 4; ++r) {
                    const int m = m0 + wm * 64 + mt * 16 + fq * 4 + r;
                    C[(size_t)m * DMODEL + n] = acc[mt][nt][r] + bs;
                }
        }
    }
}

// ---------------------------------------------------------------------------
// MFMA flash attention. Block = (qi, h, b), 64-row Q tile, 64-row K/V tiles.
// Wave w owns q rows 16w..16w+15; online-softmax state lives in registers
// (replicated across each 16-lane group matching the C-fragment layout).
// P round-trips through LDS to convert C-layout -> A-layout.
// ---------------------------------------------------------------------------
__global__ __launch_bounds__(256) void attn_kernel(
    const u16* __restrict__ q, const u16* __restrict__ k,
    const u16* __restrict__ v, u16* __restrict__ y)
{
    __shared__ u16 Qs[64 * 64];   // [q_row][d], swizzled
    __shared__ u16 Ks[64 * 64];   // [j][d], swizzled
    __shared__ u16 Ps[64 * 64];   // [q_row][j], swizzled
    __shared__ u16 Vt[64 * 72];   // [d][j], padded rows (72), not swizzled

    const int qi = blockIdx.x, hh = blockIdx.y, bb = blockIdx.z;
    const int q0 = qi * 64;
    const size_t hb = ((size_t)(bb * NH + hh)) * T_SEQ * HD;
    const u16* qb = q + hb;
    const u16* kb = k + hb;
    const u16* vb = v + hb;

    const int tid = threadIdx.x;
    const int l = tid & 63;
    const int w = tid >> 6;
    const int srow = l >> 3;
    const int sch = (l & 7) ^ srow;
    const int fr = l & 15, fq = l >> 4;

    // stage Q (wave-local rows)
#pragma unroll
    for (int ii = 0; ii < 2; ++ii) {
        const int row = w * 16 + ii * 8;
        gload16(&qb[(size_t)(q0 + row + srow) * HD + sch * 8], &Qs[row * 64]);
    }

    const float sc = 0.125f * 1.44269504f;   // HD^-0.5 * log2(e)
    float m_run[4], l_run[4];
#pragma unroll
    for (int r = 0; r < 4; ++r) { m_run[r] = -1e30f; l_run[r] = 0.f; }
    f32x4 o_acc[4] = {};
    short8 qa[2];

    const int vt_c = tid & 7;    // d-chunk
    const int vt_t = tid >> 3;   // j row (0..31, +32)

    const int nkt = qi + 1;
    for (int kt = 0; kt < nkt; ++kt) {
        const int j0 = kt * 64;
        __syncthreads();
#pragma unroll
        for (int ii = 0; ii < 2; ++ii) {
            const int row = w * 16 + ii * 8;
            gload16(&kb[(size_t)(j0 + row + srow) * HD + sch * 8], &Ks[row * 64]);
        }
#pragma unroll
        for (int it = 0; it < 2; ++it) {
            const int t = it * 32 + vt_t;
            const short8 vv = *(const short8*)&vb[(size_t)(j0 + t) * HD + vt_c * 8];
#pragma unroll
            for (int e = 0; e < 8; ++e)
                Vt[(vt_c * 8 + e) * 72 + t] = (u16)vv[e];
        }
        __syncthreads();
        if (kt == 0) {
#pragma unroll
            for (int ks = 0; ks < 2; ++ks) {
                const int ar = w * 16 + fr;
                qa[ks] = *(const short8*)&Qs[ar * 64 + (((ks * 4 + fq) ^ (l & 7)) << 3)];
            }
        }
        // S = Q K^T
        f32x4 accs[4] = {};
#pragma unroll
        for (int ks = 0; ks < 2; ++ks) {
            short8 kf[4];
#pragma unroll
            for (int nt = 0; nt < 4; ++nt) {
                const int br = nt * 16 + fr;
                kf[nt] = *(const short8*)&Ks[br * 64 + (((ks * 4 + fq) ^ (l & 7)) << 3)];
            }
#pragma unroll
            for (int nt = 0; nt < 4; ++nt)
                accs[nt] = __builtin_amdgcn_mfma_f32_16x16x32_bf16(
                    qa[ks], kf[nt], accs[nt], 0, 0, 0);
        }
        // scale to log2 domain (+ causal mask, diagonal tile only)
#pragma unroll
        for (int nt = 0; nt < 4; ++nt)
#pragma unroll
            for (int r = 0; r < 4; ++r)
                accs[nt][r] *= sc;
        if (kt == nkt - 1) {
#pragma unroll
            for (int nt = 0; nt < 4; ++nt) {
                const int jg = j0 + nt * 16 + fr;
#pragma unroll
                for (int r = 0; r < 4; ++r) {
                    const int qg = q0 + w * 16 + fq * 4 + r;
                    if (jg > qg) accs[nt][r] = -1e30f;
                }
            }
        }
        // row max (over 4 n-tiles, then across the 16-lane group)
        float mx[4];
#pragma unroll
        for (int r = 0; r < 4; ++r) {
            mx[r] = fmaxf(fmaxf(accs[0][r], accs[1][r]), fmaxf(accs[2][r], accs[3][r]));
#pragma unroll
            for (int off = 1; off < 16; off <<= 1)
                mx[r] = fmaxf(mx[r], __shfl_xor(mx[r], off));
        }
        float alpha[4], ls[4];
#pragma unroll
        for (int r = 0; r < 4; ++r) {
            const float mn = fmaxf(m_run[r], mx[r]);
            alpha[r] = exp2f(m_run[r] - mn);
            m_run[r] = mn;
            ls[r] = 0.f;
        }
        // P = exp2(s - m), write bf16 to Ps (A-layout source)
#pragma unroll
        for (int nt = 0; nt < 4; ++nt) {
            const int chunkb = nt * 2 + ((l >> 3) & 1);
#pragma unroll
            for (int r = 0; r < 4; ++r) {
                const float p = exp2f(accs[nt][r] - m_run[r]);
                ls[r] += p;
                const int row = w * 16 + fq * 4 + r;
                Ps[row * 64 + ((chunkb ^ (row & 7)) << 3) + (l & 7)] = f2bf(p);
            }
        }
#pragma unroll
        for (int r = 0; r < 4; ++r) {
#pragma unroll
            for (int off = 1; off < 16; off <<= 1)
                ls[r] += __shfl_xor(ls[r], off);
            l_run[r] = l_run[r] * alpha[r] + ls[r];
            o_acc[0][r] *= alpha[r]; o_acc[1][r] *= alpha[r];
            o_acc[2][r] *= alpha[r]; o_acc[3][r] *= alpha[r];
        }
        __syncthreads();   // Ps visible (and lgkm drained) before A-frag reads
        // O += P V
#pragma unroll
        for (int ks = 0; ks < 2; ++ks) {
            const int ar = w * 16 + fr;
            const short8 pa = *(const short8*)&Ps[ar * 64 + (((ks * 4 + fq) ^ (l & 7)) << 3)];
            short8 vf[4];
#pragma unroll
            for (int nt = 0; nt < 4; ++nt) {
                const int dr = nt * 16 + fr;
                vf[nt] = *(const short8*)&Vt[dr * 72 + (ks * 4 + fq) * 8];
            }
#pragma unroll
            for (int nt = 0; nt < 4; ++nt)
                o_acc[nt] = __builtin_amdgcn_mfma_f32_16x16x32_bf16(
                    pa, vf[nt], o_acc[nt], 0, 0, 0);
        }
    }
    // write y [B,T,D] bf16 (proj GEMM input)
#pragma unroll
    for (int nt = 0; nt < 4; ++nt)
#pragma unroll
        for (int r = 0; r < 4; ++r) {
            const int t = q0 + w * 16 + fq * 4 + r;
            const float val = o_acc[nt][r] / l_run[r];
            y[((size_t)(bb * T_SEQ) + t) * DMODEL + hh * HD + nt * 16 + fr] = f2bf(val);
        }
}

extern "C" void kernel_launch(void* const* d_in, const int* in_sizes, int n_in,
                              void* d_out, int out_size, void* d_ws, size_t ws_size,
                              hipStream_t stream) {
    const float* x      = (const float*)d_in[0];
    const float* w_qkv  = (const float*)d_in[1];
    const float* b_qkv  = (const float*)d_in[2];
    const float* w_proj = (const float*)d_in[3];
    const float* b_proj = (const float*)d_in[4];
    float* out = (float*)d_out;

    u16* xb  = (u16*)d_ws;                       // 8388608
    u16* wqT = xb + 8388608;                     // 3072*1024
    u16* wpT = wqT + 3145728;                    // 1024*1024
    u16* qkv = wpT + 1048576;                    // 3 * QKV_ELEMS (q,k,v)
    u16* yb  = qkv + 3 * QKV_ELEMS;              // 8388608

    cast_x_kernel<<<8192, 256, 0, stream>>>((const float4*)x, xb);
    tcast_kernel<<<dim3(12, 4), 256, 0, stream>>>(w_qkv, wqT, 1024, 3072);
    tcast_kernel<<<dim3(4, 4), 256, 0, stream>>>(w_proj, wpT, 1024, 1024);
    gemm_kernel<0><<<dim3(24, 64), 256, 0, stream>>>(xb, wqT, b_qkv, (void*)qkv);
    attn_kernel<<<dim3(T_SEQ / 64, NH, B_SZ), 256, 0, stream>>>(
        qkv, qkv + QKV_ELEMS, qkv + 2 * QKV_ELEMS, yb);
    gemm_kernel<1><<<dim3(8, 64), 256, 0, stream>>>(yb, wpT, b_proj, (void*)out);
}

// Round 4
// 425.747 us; speedup vs baseline: 6.3864x; 1.2825x over previous
//
#include <hip/hip_runtime.h>
#include <hip/hip_bf16.h>

typedef unsigned short u16;
typedef short short8 __attribute__((ext_vector_type(8)));
typedef short bf16x4 __attribute__((ext_vector_type(4)));
typedef float f32x4 __attribute__((ext_vector_type(4)));

#define B_SZ 4
#define T_SEQ 2048
#define DMODEL 1024
#define NH 16
#define HD 64
#define QKV_ELEMS 8388608ull  // B*NH*T*HD

__device__ __forceinline__ u16 f2bf(float f) {
    __hip_bfloat16 h = __float2bfloat16(f);
    return __builtin_bit_cast(u16, h);
}

// async global->LDS, 16B/lane; lane i lands at base + 16*i (wave-uniform base).
__device__ __forceinline__ void gload16(const void* g, void* l) {
    __builtin_amdgcn_global_load_lds(
        (const __attribute__((address_space(1))) unsigned int*)g,
        (__attribute__((address_space(3))) unsigned int*)l, 16, 0, 0);
}

// ---------------------------------------------------------------------------
__global__ __launch_bounds__(256) void cast_x_kernel(
    const float4* __restrict__ x, u16* __restrict__ xb)
{
    const int i = blockIdx.x * 256 + threadIdx.x;
    const float4 v = x[i];
    union { u16 u[4]; uint2 d; } p;
    p.u[0] = f2bf(v.x); p.u[1] = f2bf(v.y); p.u[2] = f2bf(v.z); p.u[3] = f2bf(v.w);
    *(uint2*)(xb + (size_t)i * 4) = p.d;
}

__global__ __launch_bounds__(256) void tcast_kernel(
    const float* __restrict__ w, u16* __restrict__ wt, int K, int N)
{
    const int n = blockIdx.x * 256 + threadIdx.x;
    const int k0 = blockIdx.y * 256;
    for (int kk = 0; kk < 256; kk += 8) {
        short8 o;
#pragma unroll
        for (int e = 0; e < 8; ++e)
            o[e] = (short)f2bf(w[(size_t)(k0 + kk + e) * N + n]);
        *(short8*)&wt[(size_t)n * K + k0 + kk] = o;
    }
}

// ---------------------------------------------------------------------------
// bf16 MFMA GEMM 128x128xBK64 (m97 structure). EPI=0: scatter q/k into
// [B,H,T,HD] and V TRANSPOSED into [B,H,HD,T]. EPI=1: fp32 out.
// ---------------------------------------------------------------------------
template <int EPI>
__global__ __launch_bounds__(256) void gemm_kernel(
    const u16* __restrict__ A, const u16* __restrict__ Bt,
    const float* __restrict__ bias, void* __restrict__ outp)
{
    __shared__ u16 As[128 * 64];
    __shared__ u16 Bs[128 * 64];
    const int tid = threadIdx.x;
    const int l = tid & 63;
    const int w = tid >> 6;
    const int wm = w >> 1, wn = w & 1;
    const int m0 = blockIdx.y * 128, n0 = blockIdx.x * 128;
    const int srow = l >> 3;
    const int sch  = (l & 7) ^ srow;
    const int fr = l & 15, fq = l >> 4;

    f32x4 acc[4][4] = {};

    for (int k0 = 0; k0 < 1024; k0 += 64) {
        __syncthreads();
#pragma unroll
        for (int ii = 0; ii < 4; ++ii) {
            const int row = w * 32 + ii * 8;
            gload16(&A[(size_t)(m0 + row + srow) * 1024 + k0 + sch * 8], &As[row * 64]);
            gload16(&Bt[(size_t)(n0 + row + srow) * 1024 + k0 + sch * 8], &Bs[row * 64]);
        }
        __syncthreads();
#pragma unroll
        for (int ks = 0; ks < 2; ++ks) {
            short8 af[4], bf[4];
#pragma unroll
            for (int t = 0; t < 4; ++t) {
                const int ar = wm * 64 + t * 16 + fr;
                af[t] = *(const short8*)&As[ar * 64 + (((ks * 4 + fq) ^ (l & 7)) << 3)];
                const int br = wn * 64 + t * 16 + fr;
                bf[t] = *(const short8*)&Bs[br * 64 + (((ks * 4 + fq) ^ (l & 7)) << 3)];
            }
#pragma unroll
            for (int mt = 0; mt < 4; ++mt)
#pragma unroll
                for (int nt = 0; nt < 4; ++nt)
                    acc[mt][nt] = __builtin_amdgcn_mfma_f32_16x16x32_bf16(
                        af[mt], bf[nt], acc[mt][nt], 0, 0, 0);
        }
    }

    if (EPI == 0) {
        u16* qkv = (u16*)outp;
#pragma unroll
        for (int nt = 0; nt < 4; ++nt) {
            const int n = n0 + wn * 64 + nt * 16 + fr;
            const float bs = bias[n];
            const int which = n >> 10, hh = (n >> 6) & 15, d = n & 63;
            if (which == 2) {
                // V transposed: [b][h][d][t]
                u16* dst = qkv + 2 * QKV_ELEMS;
#pragma unroll
                for (int mt = 0; mt < 4; ++mt)
#pragma unroll
                    for (int r = 0; r < 4; ++r) {
                        const int m = m0 + wm * 64 + mt * 16 + fq * 4 + r;
                        const int bb = m >> 11, t = m & 2047;
                        dst[(((size_t)(bb * NH + hh)) * HD + d) * T_SEQ + t] =
                            f2bf(acc[mt][nt][r] + bs);
                    }
            } else {
                u16* dst = qkv + (size_t)which * QKV_ELEMS + (size_t)hh * T_SEQ * HD + d;
#pragma unroll
                for (int mt = 0; mt < 4; ++mt)
#pragma unroll
                    for (int r = 0; r < 4; ++r) {
                        const int m = m0 + wm * 64 + mt * 16 + fq * 4 + r;
                        const int bb = m >> 11, t = m & 2047;
                        dst[(size_t)bb * (NH * T_SEQ * HD) + (size_t)t * HD] =
                            f2bf(acc[mt][nt][r] + bs);
                    }
            }
        }
    } else {
        float* C = (float*)outp;
#pragma unroll
        for (int nt = 0; nt < 4; ++nt) {
            const int n = n0 + wn * 64 + nt * 16 + fr;
            const float bs = bias[n];
#pragma unroll
            for (int mt = 0; mt < 4; ++mt)
#pragma unroll
                for (int r = 0; r < 4; ++r) {
                    const int m = m0 + wm * 64 + mt * 16 + fq * 4 + r;
                    C[(size_t)m * DMODEL + n] = acc[mt][nt][r] + bs;
                }
        }
    }
}

// ---------------------------------------------------------------------------
// MFMA flash attention, register-resident P.
// Block = (qi,h,b); 128 q rows; wave w owns rows {w*16+mt*64}, mt=0,1.
// S^T = K Q^T (C-layout col=q, row=j) -> pack -> B-operand of 16x16x16 PV
// MFMA computing O^T = V^T P^T. K/V^T double-buffered via global_load_lds.
// ---------------------------------------------------------------------------
__global__ __launch_bounds__(256) void attn_kernel(
    const u16* __restrict__ q, const u16* __restrict__ k,
    const u16* __restrict__ vT, u16* __restrict__ y)
{
    __shared__ u16 Qs[128 * 64];     // 16 KB, swizzled rows of 128B
    __shared__ u16 Ks[2][64 * 64];   // 16 KB  [j][d]
    __shared__ u16 Vs[2][64 * 64];   // 16 KB  [d][t]

    const int qi = (gridDim.x - 1) - blockIdx.x;   // big blocks first
    const int hh = blockIdx.y, bb = blockIdx.z;
    const int q0 = qi * 128;
    const size_t hbase = ((size_t)(bb * NH + hh)) * T_SEQ * HD;
    const u16* qb = q + hbase;
    const u16* kb = k + hbase;
    const u16* vTb = vT + hbase;     // [d][t]

    const int tid = threadIdx.x;
    const int l = tid & 63;
    const int w = tid >> 6;
    const int fr = l & 15, fq = l >> 4;
    const int srow = l >> 3;
    const int sch = (l & 7) ^ srow;

    // stage Q (128 rows) + K/V tile 0
#pragma unroll
    for (int ii = 0; ii < 4; ++ii) {
        const int row = w * 32 + ii * 8;
        gload16(&qb[(size_t)(q0 + row + srow) * HD + sch * 8], &Qs[row * 64]);
    }
    {
        const int row = w * 16, row2 = w * 16 + 8;
        gload16(&kb[(size_t)(row + srow) * HD + sch * 8], &Ks[0][row * 64]);
        gload16(&kb[(size_t)(row2 + srow) * HD + sch * 8], &Ks[0][row2 * 64]);
        gload16(&vTb[(size_t)(row + srow) * T_SEQ + sch * 8], &Vs[0][row * 64]);
        gload16(&vTb[(size_t)(row2 + srow) * T_SEQ + sch * 8], &Vs[0][row2 * 64]);
    }
    __syncthreads();

    // hoist Q fragments (B-operand: lane n=q=fr)
    short8 qf[2][2];
#pragma unroll
    for (int mt = 0; mt < 2; ++mt)
#pragma unroll
        for (int ks = 0; ks < 2; ++ks)
            qf[mt][ks] = *(const short8*)
                &Qs[(mt * 64 + w * 16 + fr) * 64 + (((ks * 4 + fq) ^ (fr & 7)) << 3)];

    const float sc = 0.125f * 1.44269504f;
    float m_run[2] = {-1e30f, -1e30f}, l_run[2] = {0.f, 0.f};
    f32x4 o_acc[2][4] = {};   // [mt][dt], O^T: row=d, col=q

    const int nkt = 2 * (qi + 1);
    for (int kt = 0; kt < nkt; ++kt) {
        if (kt > 0) __syncthreads();
        if (kt + 1 < nkt) {
            const int nb = (kt + 1) & 1;
            const int jj = (kt + 1) * 64;
            const int row = w * 16, row2 = w * 16 + 8;
            gload16(&kb[(size_t)(jj + row + srow) * HD + sch * 8], &Ks[nb][row * 64]);
            gload16(&kb[(size_t)(jj + row2 + srow) * HD + sch * 8], &Ks[nb][row2 * 64]);
            gload16(&vTb[(size_t)(row + srow) * T_SEQ + jj + sch * 8], &Vs[nb][row * 64]);
            gload16(&vTb[(size_t)(row2 + srow) * T_SEQ + jj + sch * 8], &Vs[nb][row2 * 64]);
        }
        const int buf = kt & 1;
        const int j0 = kt * 64;

        // K fragments (A-operand: lane m=j=fr within 16-row subtile jt)
        short8 kf[4][2];
#pragma unroll
        for (int jt = 0; jt < 4; ++jt)
#pragma unroll
            for (int ks = 0; ks < 2; ++ks)
                kf[jt][ks] = *(const short8*)
                    &Ks[buf][(jt * 16 + fr) * 64 + (((ks * 4 + fq) ^ (fr & 7)) << 3)];

        // V^T fragments for PV (A-operand of 16x16x16: k=quad*4+idx)
        bf16x4 vf[4][4];
#pragma unroll
        for (int dt = 0; dt < 4; ++dt)
#pragma unroll
            for (int jt = 0; jt < 4; ++jt)
                vf[dt][jt] = *(const bf16x4*)
                    &Vs[buf][(dt * 16 + fr) * 64 +
                             (((2 * jt + (fq >> 1)) ^ (fr & 7)) << 3) + ((fq & 1) << 2)];

#pragma unroll
        for (int mt = 0; mt < 2; ++mt) {
            const int qbase = q0 + mt * 64 + w * 16;
            if (j0 >= qbase + 16) continue;      // fully masked sub-tile

            f32x4 st[4] = {};
#pragma unroll
            for (int ks = 0; ks < 2; ++ks)
#pragma unroll
                for (int jt = 0; jt < 4; ++jt)
                    st[jt] = __builtin_amdgcn_mfma_f32_16x16x32_bf16(
                        kf[jt][ks], qf[mt][ks], st[jt], 0, 0, 0);

            const int qg = qbase + fr;
            const bool needMask = (j0 + 63 > qbase);
#pragma unroll
            for (int jt = 0; jt < 4; ++jt)
#pragma unroll
                for (int r = 0; r < 4; ++r) {
                    float s = st[jt][r] * sc;
                    if (needMask) {
                        const int jg = j0 + jt * 16 + fq * 4 + r;
                        if (jg > qg) s = -1e30f;
                    }
                    st[jt][r] = s;
                }

            float mx = -1e30f;
#pragma unroll
            for (int jt = 0; jt < 4; ++jt)
#pragma unroll
                for (int r = 0; r < 4; ++r) mx = fmaxf(mx, st[jt][r]);
            mx = fmaxf(mx, __shfl_xor(mx, 16));
            mx = fmaxf(mx, __shfl_xor(mx, 32));
            const float mn = fmaxf(m_run[mt], mx);
            const float alpha = exp2f(m_run[mt] - mn);
            m_run[mt] = mn;

            float ls = 0.f;
            bf16x4 pk[4];
#pragma unroll
            for (int jt = 0; jt < 4; ++jt)
#pragma unroll
                for (int r = 0; r < 4; ++r) {
                    const float p = exp2f(st[jt][r] - mn);
                    ls += p;
                    pk[jt][r] = (short)f2bf(p);
                }
            ls += __shfl_xor(ls, 16);
            ls += __shfl_xor(ls, 32);
            l_run[mt] = l_run[mt] * alpha + ls;

#pragma unroll
            for (int dt = 0; dt < 4; ++dt) o_acc[mt][dt] *= alpha;

#pragma unroll
            for (int dt = 0; dt < 4; ++dt)
#pragma unroll
                for (int jt = 0; jt < 4; ++jt)
                    o_acc[mt][dt] = __builtin_amdgcn_mfma_f32_16x16x16bf16_1k(
                        vf[dt][jt], pk[jt], o_acc[mt][dt], 0, 0, 0);
        }
    }

    // write y [B,T,D] bf16; lane holds d=dt*16+fq*4+r, t=q0+mt*64+w*16+fr
#pragma unroll
    for (int mt = 0; mt < 2; ++mt) {
        const float inv = 1.f / l_run[mt];
        const int t = q0 + mt * 64 + w * 16 + fr;
#pragma unroll
        for (int dt = 0; dt < 4; ++dt) {
            bf16x4 ov;
#pragma unroll
            for (int r = 0; r < 4; ++r) ov[r] = (short)f2bf(o_acc[mt][dt][r] * inv);
            *(bf16x4*)&y[((size_t)(bb * T_SEQ + t)) * DMODEL + hh * HD + dt * 16 + fq * 4] = ov;
        }
    }
}

extern "C" void kernel_launch(void* const* d_in, const int* in_sizes, int n_in,
                              void* d_out, int out_size, void* d_ws, size_t ws_size,
                              hipStream_t stream) {
    const float* x      = (const float*)d_in[0];
    const float* w_qkv  = (const float*)d_in[1];
    const float* b_qkv  = (const float*)d_in[2];
    const float* w_proj = (const float*)d_in[3];
    const float* b_proj = (const float*)d_in[4];
    float* out = (float*)d_out;

    u16* xb  = (u16*)d_ws;
    u16* wqT = xb + 8388608;
    u16* wpT = wqT + 3145728;
    u16* qkv = wpT + 1048576;           // q | k | vT
    u16* yb  = qkv + 3 * QKV_ELEMS;

    cast_x_kernel<<<8192, 256, 0, stream>>>((const float4*)x, xb);
    tcast_kernel<<<dim3(12, 4), 256, 0, stream>>>(w_qkv, wqT, 1024, 3072);
    tcast_kernel<<<dim3(4, 4), 256, 0, stream>>>(w_proj, wpT, 1024, 1024);
    gemm_kernel<0><<<dim3(24, 64), 256, 0, stream>>>(xb, wqT, b_qkv, (void*)qkv);
    attn_kernel<<<dim3(T_SEQ / 128, NH, B_SZ), 256, 0, stream>>>(
        qkv, qkv + QKV_ELEMS, qkv + 2 * QKV_ELEMS, yb);
    gemm_kernel<1><<<dim3(8, 64), 256, 0, stream>>>(yb, wpT, b_proj, (void*)out);
}